// Round 1
// baseline (9696.853 us; speedup 1.0000x reference)
//
#include <hip/hip_runtime.h>
#include <hip/hip_bf16.h>

#define T_SEQ 512
#define BATCH 128
#define D_IN 1024
#define D_OUT 1024
#define D_XH 2048   // D_IN + D_OUT

typedef __bf16 bf16_t;
typedef __bf16 bf16x8 __attribute__((ext_vector_type(8)));
typedef float f32x4 __attribute__((ext_vector_type(4)));

// ---- workspace layout (bytes) ----
// Wp   bf16 [4][1024][2048] : 0        .. 16777216
// bias f32  [4096]          : 16777216 .. +16384
// h    bf16 [2][128][1024]  : 16793600 .. +524288
// c    f32  [128][1024]     : 17317888 .. +524288   (total ~17.8 MB)
#define WS_BIAS 16777216
#define WS_H    (WS_BIAS + 16384)
#define WS_C    (WS_H + 2 * 128 * 1024 * 2)

__device__ __forceinline__ float sigm(float x) {
    return 1.0f / (1.0f + __expf(-x));
}
__device__ __forceinline__ float tanh_f(float x) {
    // NaN-free for large |x|: e^{-2x} -> 0 or inf, both fine
    return 2.0f / (1.0f + __expf(-2.0f * x)) - 1.0f;
}

// Repack 4 gate weight matrices fp32 -> bf16, gate-major [4][1024][2048]
__global__ void pack_weights(const float* __restrict__ Wf, const float* __restrict__ Wi,
                             const float* __restrict__ Wc, const float* __restrict__ Wo,
                             bf16_t* __restrict__ Wp) {
    int idx = blockIdx.x * blockDim.x + threadIdx.x;   // float4-group index
    if (idx >= 4 * 1024 * 2048 / 4) return;
    int g  = idx >> 19;          // 524288 float4 groups per gate
    int rk = idx & 524287;
    const float* src = (g == 0) ? Wf : (g == 1) ? Wi : (g == 2) ? Wc : Wo;
    float4 v = ((const float4*)src)[rk];
    bf16_t* dst = Wp + (size_t)g * (1024 * 2048) + (size_t)rk * 4;
    dst[0] = (bf16_t)v.x; dst[1] = (bf16_t)v.y;
    dst[2] = (bf16_t)v.z; dst[3] = (bf16_t)v.w;
}

// Pack biases into [4096] (gate-major f,i,c,o) and zero h0 / c state
__global__ void init_state(const float* __restrict__ bf, const float* __restrict__ bi,
                           const float* __restrict__ bc, const float* __restrict__ bo,
                           float* __restrict__ bias, bf16_t* __restrict__ h0,
                           float* __restrict__ c) {
    int idx = blockIdx.x * blockDim.x + threadIdx.x;
    if (idx < 1024) {
        bias[idx]        = bf[idx];
        bias[1024 + idx] = bi[idx];
        bias[2048 + idx] = bc[idx];
        bias[3072 + idx] = bo[idx];
    }
    if (idx < 128 * 1024) {
        h0[idx] = (bf16_t)0.0f;
        c[idx]  = 0.0f;
    }
}

#define BK 256
#define LDST (BK + 8)   // +8 bf16 pad -> 2-way LDS bank aliasing (free)

// One LSTM timestep. Grid: 256 blocks = 4 batch-splits x 64 r-tiles; 256 threads (4 waves).
// Block computes pre-activations for all 4 gates on [32 b x 16 r], K = 2048.
__global__ __launch_bounds__(256)
void lstm_step(const float* __restrict__ x_t,    // [128][1024] fp32 (tokens slice)
               const bf16_t* __restrict__ Wp,    // [4][1024][2048] bf16
               const float* __restrict__ bias,   // [4096]
               const bf16_t* __restrict__ h_in,  // [128][1024]
               bf16_t* __restrict__ h_out,       // [128][1024]
               float* __restrict__ c,            // [128][1024]
               float* __restrict__ out_t) {      // [128][1024] fp32
    __shared__ bf16_t xh_lds[32][LDST];
    __shared__ bf16_t w_lds[64][LDST];
    __shared__ float  pre_lds[4][32][16];

    const int tid  = threadIdx.x;
    const int wave = tid >> 6;
    const int lane = tid & 63;
    const int rblk = blockIdx.x & 63;   // 64 r-tiles
    const int mblk = blockIdx.x >> 6;   // 4 batch splits
    const int r0 = rblk * 16;
    const int m0 = mblk * 32;

    const int mt   = wave & 1;          // which 16-row M-tile of the 32
    const int gp   = wave >> 1;         // gate pair {0,1} or {2,3}
    const int col  = lane & 15;
    const int quad = lane >> 4;

    f32x4 acc0 = {0.f, 0.f, 0.f, 0.f};
    f32x4 acc1 = {0.f, 0.f, 0.f, 0.f};

    for (int k0 = 0; k0 < D_XH; k0 += BK) {
        // ---- stage xh chunk [32][BK] into LDS ----
        if (k0 < D_IN) {
            // x part: fp32 -> bf16 on the fly
            #pragma unroll
            for (int it = 0; it < 8; ++it) {
                int idx = it * 256 + tid;      // 2048 float4 groups
                int row = idx >> 6;
                int c4  = idx & 63;
                float4 v = *(const float4*)(x_t + (size_t)(m0 + row) * D_IN + k0 + c4 * 4);
                bf16_t* dst = &xh_lds[row][c4 * 4];
                dst[0] = (bf16_t)v.x; dst[1] = (bf16_t)v.y;
                dst[2] = (bf16_t)v.z; dst[3] = (bf16_t)v.w;
            }
        } else {
            // h part: already bf16
            #pragma unroll
            for (int it = 0; it < 4; ++it) {
                int idx = it * 256 + tid;      // 1024 groups of 8 bf16
                int row = idx >> 5;
                int c8  = idx & 31;
                uint4 v = *(const uint4*)(h_in + (size_t)(m0 + row) * D_OUT + (k0 - D_IN) + c8 * 8);
                *(uint4*)&xh_lds[row][c8 * 8] = v;
            }
        }
        // ---- stage W chunk [64][BK] (rows = gate*16 + r_local) ----
        #pragma unroll
        for (int it = 0; it < 8; ++it) {
            int idx = it * 256 + tid;          // 2048 groups of 8 bf16
            int row = idx >> 5;                // 0..63
            int c8  = idx & 31;
            int g = row >> 4, rl = row & 15;
            uint4 v = *(const uint4*)(Wp + (size_t)(g * 1024 + r0 + rl) * D_XH + k0 + c8 * 8);
            *(uint4*)&w_lds[row][c8 * 8] = v;
        }
        __syncthreads();

        // ---- MFMA over this K chunk ----
        #pragma unroll
        for (int kk = 0; kk < BK; kk += 32) {
            bf16x8 a  = *(const bf16x8*)&xh_lds[mt * 16 + col][kk + quad * 8];
            bf16x8 b0 = *(const bf16x8*)&w_lds[(2 * gp) * 16 + col][kk + quad * 8];
            bf16x8 b1 = *(const bf16x8*)&w_lds[(2 * gp + 1) * 16 + col][kk + quad * 8];
            acc0 = __builtin_amdgcn_mfma_f32_16x16x32_bf16(a, b0, acc0, 0, 0, 0);
            acc1 = __builtin_amdgcn_mfma_f32_16x16x32_bf16(a, b1, acc1, 0, 0, 0);
        }
        __syncthreads();
    }

    // ---- gather pre-activations: D layout col=lane&15, row=quad*4+i ----
    int b_base = mt * 16 + quad * 4;
    #pragma unroll
    for (int i = 0; i < 4; ++i) {
        pre_lds[2 * gp][b_base + i][col]     = acc0[i];
        pre_lds[2 * gp + 1][b_base + i][col] = acc1[i];
    }
    __syncthreads();

    // ---- pointwise epilogue: 512 elems over 256 threads ----
    #pragma unroll
    for (int j = 0; j < 2; ++j) {
        int e  = j * 256 + tid;
        int bl = e >> 4;
        int r  = e & 15;
        int d  = r0 + r;
        int bg = m0 + bl;
        float pf = pre_lds[0][bl][r] + bias[d];
        float pi = pre_lds[1][bl][r] + bias[1024 + d];
        float pc = pre_lds[2][bl][r] + bias[2048 + d];
        float po = pre_lds[3][bl][r] + bias[3072 + d];
        float fg = sigm(pf);
        float ig = sigm(pi);
        float gg = tanh_f(pc);
        float og = sigm(po);
        size_t off = (size_t)bg * D_OUT + d;
        float cn = c[off] * fg + ig * gg;
        c[off] = cn;
        float h = og * tanh_f(cn);
        out_t[off] = h;
        h_out[off] = (bf16_t)h;
    }
}

extern "C" void kernel_launch(void* const* d_in, const int* in_sizes, int n_in,
                              void* d_out, int out_size, void* d_ws, size_t ws_size,
                              hipStream_t stream) {
    const float* tokens = (const float*)d_in[0];
    const float* Wf = (const float*)d_in[1];
    const float* bf = (const float*)d_in[2];
    const float* Wi = (const float*)d_in[3];
    const float* bi = (const float*)d_in[4];
    const float* Wc = (const float*)d_in[5];
    const float* bc = (const float*)d_in[6];
    const float* Wo = (const float*)d_in[7];
    const float* bo = (const float*)d_in[8];
    float* out = (float*)d_out;

    char* ws = (char*)d_ws;
    bf16_t* Wp   = (bf16_t*)(ws);
    float*  bias = (float*)(ws + WS_BIAS);
    bf16_t* hbuf = (bf16_t*)(ws + WS_H);    // [2][128*1024]
    float*  cbuf = (float*)(ws + WS_C);

    // repack weights (8.4M elems, 2.1M float4 groups)
    pack_weights<<<(4 * 1024 * 2048 / 4 + 255) / 256, 256, 0, stream>>>(Wf, Wi, Wc, Wo, Wp);
    init_state<<<(128 * 1024 + 255) / 256, 256, 0, stream>>>(bf, bi, bc, bo, bias, hbuf, cbuf);

    for (int t = 0; t < T_SEQ; ++t) {
        const bf16_t* h_in  = hbuf + (size_t)(t & 1) * (128 * 1024);
        bf16_t*       h_out = hbuf + (size_t)((t + 1) & 1) * (128 * 1024);
        lstm_step<<<256, 256, 0, stream>>>(tokens + (size_t)t * BATCH * D_IN, Wp, bias,
                                           h_in, h_out, cbuf,
                                           out + (size_t)t * BATCH * D_OUT);
    }
}